// Round 17
// baseline (61.175 us; speedup 1.0000x reference)
//
#include <hip/hip_runtime.h>
#include <cmath>

typedef float  f32x4  __attribute__((ext_vector_type(4)));
typedef __bf16 bf16x8 __attribute__((ext_vector_type(8)));
typedef unsigned int u32x4 __attribute__((ext_vector_type(4)));
typedef unsigned int u32x2 __attribute__((ext_vector_type(2)));
typedef unsigned int   u32;
typedef unsigned short u16;

#define HEAD_DIM 64
#define N_HEADS  25
#define N_KV     5
#define WINDOW   1024
#define N_META   128
#define B_       2
#define T_       2048
#define QB       64
#define NTILES   (T_ / 64)
#define TILE_U32 2048               // 64 rows x 32 u32 (8 KB)
// Constant softmax bias: S*0.125*log2e <= (8*1.5)^2*0.125*1.443 ~= 26 (RMSNorm-guaranteed,
// w in [0.5,1.5]). exp2(S-20) <= 64; l <= 6.6e4; min ~= 2^-46 (normal). Scale cancels in O/l.
// Constant bias (no max-merge) is what makes split-K partial sums exactly additive.
#define SM_BIAS  (-20.0f)

static __device__ __forceinline__ u16 bf16_bits(float f) {
  __bf16 h = (__bf16)f;
  return __builtin_bit_cast(u16, h);
}
static __device__ __forceinline__ u32 pack2(float lo, float hi) {
  return ((u32)bf16_bits(hi) << 16) | bf16_bits(lo);
}
static __device__ __forceinline__ float fexp2(float x) {
  return __builtin_amdgcn_exp2f(x);    // bare v_exp_f32; exp2(-inf)=0
}
static __device__ __forceinline__ void gload16(const u32* g, u32* l) {
  __builtin_amdgcn_global_load_lds((const __attribute__((address_space(1))) u32*)g,
                                   (__attribute__((address_space(3))) u32*)l, 16, 0, 0);
}

// ---------------- Kernel 1: K RMSNorm+RoPE -> bf16 tiles, seg-XOR pre-swizzled ----------
// [b][kvh][tile][key(64)][seg_phys(8) x 4 u32]; seg_phys = seg_log ^ (key&7)
__global__ __launch_bounds__(256) void prep_k_kernel(
    const float* __restrict__ k_in, const float* __restrict__ k_w,
    const int* __restrict__ pos_ids, u32* __restrict__ k_ws)
{
  int gw   = (blockIdx.x * blockDim.x + threadIdx.x) >> 6;
  int lane = threadIdx.x & 63;
  if (gw >= B_ * T_ * N_KV) return;
  int kvh = gw % N_KV;
  int bt  = gw / N_KV;

  float x = k_in[(size_t)bt * (N_KV * HEAD_DIM) + kvh * HEAD_DIM + lane];
  float ss = x * x;
  #pragma unroll
  for (int off = 32; off; off >>= 1) ss += __shfl_xor(ss, off);
  float y = k_w[lane] * x * rsqrtf(ss * (1.f / 64.f) + 1e-6f);

  int   pos = pos_ids[bt];
  float ang = (float)pos * powf(10000.f, -(float)(lane & 31) * (1.f / 32.f));
  float c, s;
  sincosf(ang, &s, &c);              // sincosf(x, sin*, cos*)
  float part = __shfl_xor(y, 32);
  float r = (lane < 32) ? (y * c - part * s) : (y * c + part * s);

  u16 mybits = bf16_bits(r);
  u32 pb = (u32)(u16)__shfl_xor((int)mybits, 1);
  u32 w  = (pb << 16) | mybits;
  int b = bt / T_, t = bt % T_;
  if (!(lane & 1)) {
    int c32 = lane >> 1;
    int kl = t & 63, tile = t >> 6;
    int sp = (c32 >> 2) ^ (kl & 7);
    k_ws[(((size_t)(b * N_KV + kvh) * NTILES + tile)) * TILE_U32 + kl * 32 + sp * 4 + (c32 & 3)] = w;
  }
}

// ---------------- Kernel 1b: V -> bf16 V^T tiles, b128 K-group pre-swizzled ------------
// [b][kvh][tile][d(64)][32 u32]. Logical u32 col c holds keys (2c,2c+1). c = 16a+8b+2g+e
// stored at phys seg sp = (4a+g)^(d&7), slot 2b+e. attn's b128 read at seg (4kw+g)^(d&7)
// yields keys {32kw+4g+0..3, 32kw+16+4g+0..3} = the PV A-frag k-order for wave kw.
__global__ __launch_bounds__(256) void prep_v_kernel(
    const float* __restrict__ v_in, u32* __restrict__ v_ws)
{
  int blk  = blockIdx.x;
  int tile = blk & (NTILES - 1);
  int bk   = blk >> 5;
  int kvh  = bk % N_KV, b = bk / N_KV;
  int t0   = tile * 64;
  int tid  = threadIdx.x;

  __shared__ u16 Tl[64][72];             // [d][key]

  #pragma unroll
  for (int it = 0; it < 4; ++it) {
    int idx = it * 256 + tid;
    int kl = idx >> 4, dq = idx & 15;
    const float4 f = *(const float4*)&v_in[((size_t)(b * T_ + t0 + kl)) * (N_KV * HEAD_DIM) + kvh * HEAD_DIM + dq * 4];
    Tl[dq * 4 + 0][kl] = bf16_bits(f.x);
    Tl[dq * 4 + 1][kl] = bf16_bits(f.y);
    Tl[dq * 4 + 2][kl] = bf16_bits(f.z);
    Tl[dq * 4 + 3][kl] = bf16_bits(f.w);
  }
  __syncthreads();

  u32* outb = v_ws + (size_t)blk * TILE_U32;
  #pragma unroll
  for (int it = 0; it < 8; ++it) {
    int o = it * 256 + tid;
    int d = o >> 5, c = o & 31;
    u32 w = ((u32)Tl[d][2 * c + 1] << 16) | Tl[d][2 * c];
    int a = c >> 4, bs = (c >> 3) & 1, gp = (c >> 1) & 3, e = c & 1;
    int sp = (4 * a + gp) ^ (d & 7);
    outb[d * 32 + sp * 4 + 2 * bs + e] = w;
  }
}

// ---------------- Kernel 2: fused MFMA flash attention (split-K 2x2 wave grid) ---------
// Wave (qw,kw) owns 32 queries x 32 keys per tile: kf/vf DS reads 16 -> 8 b128/wave-tile.
// Constant-bias softmax makes partial (O,l) additive; cross-kw reduce once at epilogue.
__global__ __launch_bounds__(256, 4) void attn_kernel(
    const float* __restrict__ q_in, const float* __restrict__ q_w,
    const int* __restrict__ pos_ids,
    const u32* __restrict__ kws, const u32* __restrict__ vws,
    float* __restrict__ out)
{
  // XCD-affinity + LPT decode (r14; FETCH 44.8->16.5MB proven).
  const int i  = blockIdx.x;
  const int x  = i & 7, k = i >> 3;
  const int gA = (5 * x) >> 2;
  const int a0 = 200 * x - 160 * gA;
  const int nB = 40 + a0;
  int grp, j_;
  if (k < nB) { grp = gA + 1; j_ = k; }
  else        { grp = gA;     j_ = a0 + (k - nB); }
  const int qt  = 31 - j_ / 5;
  const int hh  = j_ % 5;
  const int b   = grp / 5;
  const int kvh = grp % 5;
  const int h   = kvh * 5 + hh;
  const int qb  = qt * QB;
  const int tid = threadIdx.x, wid = tid >> 6, lane = tid & 63;
  const int l15 = lane & 15, g = lane >> 4;
  const int qw  = wid >> 1, kw = wid & 1;          // 2x2 wave grid

  __shared__ u32 Ks[2 * TILE_U32];       // K tiles (buf1 doubles as Q staging pre-loop)
  __shared__ u32 Vt[2 * TILE_U32];       // V^T tiles (epilogue: cross-kw xfer buffers)

  const int nt    = (qt <= 18) ? (qt + 1) : 19;
  const int shift = qt - 18;

  const size_t kvbase = ((size_t)(b * N_KV + kvh)) * NTILES * TILE_U32;
  const u32* kb = kws + kvbase;
  const u32* vb = vws + kvbase;

  // ---- issue tile-0 staging first (hides under Q-staging compute) ----
  #pragma unroll
  for (int j = 0; j < 4; ++j) {
    int ci = (wid << 2) | j;
    if (ci < 8) gload16(kb + ci * 256 + lane * 4, &Ks[ci * 256]);
    else        gload16(vb + (ci - 8) * 256 + lane * 4, &Vt[(ci - 8) * 256]);
  }

  // ---- Q staging, 4-rows-parallel (r16): wave wid stages rows 16*wid + 4*it + g ----
  {
    const int   jbase = (4 * l15) & 31;
    const float r32   = 0.74989420933f;            // 10000^(-1/32)
    float fr[4];
    fr[0] = powf(10000.f, -(float)jbase * (1.f / 32.f));
    fr[1] = fr[0] * r32; fr[2] = fr[1] * r32; fr[3] = fr[2] * r32;

    const int t0g = b * T_ + qb + wid * 16;
    int pos_prev = pos_ids[t0g + g];
    float cc[4], sn[4], c4[4], s4[4];
    #pragma unroll
    for (int e = 0; e < 4; ++e) {
      sincosf((float)pos_prev * fr[e], &sn[e], &cc[e]);   // sincosf(x, sin*, cos*)
      sincosf(4.f * fr[e], &s4[e], &c4[e]);
    }
    const float4 wv = *(const float4*)&q_w[4 * l15];
    #pragma unroll
    for (int it = 0; it < 4; ++it) {
      const int row = 4 * it + g;
      if (it) {
        int pos = pos_ids[t0g + row];
        if (__all(pos == pos_prev + 4)) {
          #pragma unroll
          for (int e = 0; e < 4; ++e) {
            float c2 = cc[e] * c4[e] - sn[e] * s4[e];
            sn[e] = sn[e] * c4[e] + cc[e] * s4[e];
            cc[e] = c2;
          }
        } else {
          #pragma unroll
          for (int e = 0; e < 4; ++e) sincosf((float)pos * fr[e], &sn[e], &cc[e]);
        }
        pos_prev = pos;
      }
      const float4 xv = *(const float4*)&q_in[((size_t)(t0g + row)) * (N_HEADS * HEAD_DIM) + h * HEAD_DIM + 4 * l15];
      float ss = xv.x * xv.x + xv.y * xv.y + xv.z * xv.z + xv.w * xv.w;
      ss += __shfl_xor(ss, 1); ss += __shfl_xor(ss, 2);
      ss += __shfl_xor(ss, 4); ss += __shfl_xor(ss, 8);
      const float rn = rsqrtf(ss * (1.f / 64.f) + 1e-6f);
      float y[4] = {wv.x * xv.x * rn, wv.y * xv.y * rn, wv.z * xv.z * rn, wv.w * xv.w * rn};
      float rv[4];
      #pragma unroll
      for (int e = 0; e < 4; ++e) {
        float part = __shfl_xor(y[e], 8);
        rv[e] = ((l15 < 8) ? (y[e] * cc[e] - part * sn[e])
                           : (y[e] * cc[e] + part * sn[e])) * 0.18033688f;
      }
      u32x2 w2;
      w2.x = pack2(rv[0], rv[1]);
      w2.y = pack2(rv[2], rv[3]);
      *(u32x2*)&Ks[TILE_U32 + (wid * 16 + row) * 32 + 2 * l15] = w2;
    }
  }
  __syncthreads();                       // tile0 loads drained + all Q rows visible

  // qf for the wave's 32 queries (2 sub-frags)
  bf16x8 qf[2][2];                       // [qn][ks]
  #pragma unroll
  for (int qn = 0; qn < 2; ++qn)
    #pragma unroll
    for (int ks = 0; ks < 2; ++ks)
      qf[qn][ks] = *(const bf16x8*)&Ks[TILE_U32 + (32 * qw + 16 * qn + l15) * 32 + 16 * ks + 4 * g];
  __syncthreads();                       // all qf reads done before buf1 is overwritten

  float l_part[2] = {0.f, 0.f};          // per-lane partial of l (g- and kw-reduce deferred)
  f32x4 acc_o[2][4];                     // [qn][mt2]
  #pragma unroll
  for (int qn = 0; qn < 2; ++qn)
    #pragma unroll
    for (int mt = 0; mt < 4; ++mt) acc_o[qn][mt] = (f32x4)(0.f);

  const int q_abs0 = qb + 32 * qw + l15; // + 16*qn

  int buf = 0;
  for (int i2 = 0; i2 < nt; ++i2) {
    // ---- prefetch next tile into buf^1 ----
    if (i2 + 1 < nt) {
      int tn = (qt <= 18 || i2 + 1 < 2) ? (i2 + 1) : (i2 + 1 + shift);
      const u32* kt = kb + (size_t)tn * TILE_U32;
      const u32* vt = vb + (size_t)tn * TILE_U32;
      u32* kd = &Ks[(buf ^ 1) * TILE_U32];
      u32* vd = &Vt[(buf ^ 1) * TILE_U32];
      #pragma unroll
      for (int j = 0; j < 4; ++j) {
        int ci = (wid << 2) | j;
        if (ci < 8) gload16(kt + ci * 256 + lane * 4, kd + ci * 256);
        else        gload16(vt + (ci - 8) * 256 + lane * 4, vd + (ci - 8) * 256);
      }
    }
    const int k0 = ((qt <= 18 || i2 < 2) ? i2 : i2 + shift) << 6;

    // ---- S^T - 20 for wave's 32 keys x 32 queries (bias in MFMA C-init) ----
    f32x4 accs[2][2];                    // [qn][mt]
    #pragma unroll
    for (int qn = 0; qn < 2; ++qn)
      #pragma unroll
      for (int mt = 0; mt < 2; ++mt) accs[qn][mt] = (f32x4)(SM_BIAS);
    #pragma unroll
    for (int ks = 0; ks < 2; ++ks) {
      #pragma unroll
      for (int mt = 0; mt < 2; ++mt) {
        bf16x8 kf = *(const bf16x8*)&Ks[buf * TILE_U32 + (32 * kw + 16 * mt + l15) * 32 + (((4 * ks + g) ^ (l15 & 7)) << 2)];
        accs[0][mt] = __builtin_amdgcn_mfma_f32_16x16x32_bf16(kf, qf[0][ks], accs[0][mt], 0, 0, 0);
        accs[1][mt] = __builtin_amdgcn_mfma_f32_16x16x32_bf16(kf, qf[1][ks], accs[1][mt], 0, 0, 0);
      }
    }

    // ---- mask boundary tiles, then P = exp2(S-20) (no max tracking) ----
    const bool do_mask = (i2 == nt - 1) || (qt >= 18 && i2 == 2);
    if (do_mask) {
      #pragma unroll
      for (int qn = 0; qn < 2; ++qn)
        #pragma unroll
        for (int mt = 0; mt < 2; ++mt)
          #pragma unroll
          for (int rg = 0; rg < 4; ++rg) {
            int key = k0 + 32 * kw + 16 * mt + 4 * g + rg;
            int qa  = q_abs0 + 16 * qn;
            bool ok = (key <= qa) && ((key >= qa - (WINDOW - 1)) || (key < N_META));
            accs[qn][mt][rg] = ok ? accs[qn][mt][rg] : -INFINITY;
          }
    }
    #pragma unroll
    for (int qn = 0; qn < 2; ++qn) {
      float rsum = 0.f;
      #pragma unroll
      for (int mt = 0; mt < 2; ++mt)
        #pragma unroll
        for (int rg = 0; rg < 4; ++rg) {
          float pi = fexp2(accs[qn][mt][rg]);    // exp2(-inf) = 0
          accs[qn][mt][rg] = pi;
          rsum += pi;
        }
      l_part[qn] += rsum;
    }

    // ---- O += P·V over wave's 32 keys (K=32 MFMA; vf seg selects kw's key block) ----
    #pragma unroll
    for (int qn = 0; qn < 2; ++qn) {
      u32x4 aw;
      aw.x = pack2(accs[qn][0][0], accs[qn][0][1]);
      aw.y = pack2(accs[qn][0][2], accs[qn][0][3]);
      aw.z = pack2(accs[qn][1][0], accs[qn][1][1]);
      aw.w = pack2(accs[qn][1][2], accs[qn][1][3]);
      bf16x8 af = __builtin_bit_cast(bf16x8, aw);
      #pragma unroll
      for (int mt2 = 0; mt2 < 4; ++mt2) {
        bf16x8 vf = *(const bf16x8*)&Vt[buf * TILE_U32 + (16 * mt2 + l15) * 32 + (((4 * kw + g) ^ (l15 & 7)) << 2)];
        acc_o[qn][mt2] = __builtin_amdgcn_mfma_f32_16x16x32_bf16(af, vf, acc_o[qn][mt2], 0, 0, 0);
      }
    }

    __syncthreads();     // drains vmcnt (next tile landed) + all waves done with buf
    buf ^= 1;
  }

  // ---- cross-kw reduction: kw=1 dumps partial O,l to LDS; kw=0 adds ----
  {
    float* xbuf = (float*)(qw ? Vt : Ks);          // 34*64*4 = 8704 B < 16 KB
    if (kw) {
      #pragma unroll
      for (int qn = 0; qn < 2; ++qn)
        #pragma unroll
        for (int mt2 = 0; mt2 < 4; ++mt2)
          #pragma unroll
          for (int rg = 0; rg < 4; ++rg)
            xbuf[(qn * 16 + mt2 * 4 + rg) * 64 + lane] = acc_o[qn][mt2][rg];
      xbuf[32 * 64 + lane] = l_part[0];
      xbuf[33 * 64 + lane] = l_part[1];
    }
  }
  __syncthreads();
  if (kw == 0) {
    const float* xbuf = (const float*)(qw ? Vt : Ks);
    #pragma unroll
    for (int qn = 0; qn < 2; ++qn)
      #pragma unroll
      for (int mt2 = 0; mt2 < 4; ++mt2)
        #pragma unroll
        for (int rg = 0; rg < 4; ++rg)
          acc_o[qn][mt2][rg] += xbuf[(qn * 16 + mt2 * 4 + rg) * 64 + lane];
    l_part[0] += xbuf[32 * 64 + lane];
    l_part[1] += xbuf[33 * 64 + lane];

    // ---- epilogue: reduce l across g-groups, divide, store (queries 32qw+16qn+4g+rg) --
    #pragma unroll
    for (int qn = 0; qn < 2; ++qn) {
      float lsum = l_part[qn];
      lsum += __shfl_xor(lsum, 16);
      lsum += __shfl_xor(lsum, 32);
      float l4[4];
      #pragma unroll
      for (int rg = 0; rg < 4; ++rg) l4[rg] = __shfl(lsum, 4 * g + rg);
      #pragma unroll
      for (int mt2 = 0; mt2 < 4; ++mt2)
        #pragma unroll
        for (int rg = 0; rg < 4; ++rg) {
          int t = qb + 32 * qw + 16 * qn + 4 * g + rg;
          out[((size_t)(b * T_ + t)) * (N_HEADS * HEAD_DIM) + h * HEAD_DIM + 16 * mt2 + l15] =
              acc_o[qn][mt2][rg] / l4[rg];
        }
    }
  }
}

extern "C" void kernel_launch(void* const* d_in, const int* in_sizes, int n_in,
                              void* d_out, int out_size, void* d_ws, size_t ws_size,
                              hipStream_t stream) {
  const float* q   = (const float*)d_in[0];
  const float* k   = (const float*)d_in[1];
  const float* v   = (const float*)d_in[2];
  const float* qw  = (const float*)d_in[3];
  const float* kw  = (const float*)d_in[4];
  const int*   pos = (const int*)d_in[5];

  u32* kp = (u32*)d_ws;                                    // 2.62 MB
  u32* vp = kp + (size_t)B_ * N_KV * NTILES * TILE_U32;    // 2.62 MB
  float* outp = (float*)d_out;

  prep_k_kernel<<<5120, 256, 0, stream>>>(k, kw, pos, kp);
  prep_v_kernel<<<B_ * N_KV * NTILES, 256, 0, stream>>>(v, vp);
  attn_kernel<<<1600, 256, 0, stream>>>(q, qw, pos, kp, vp, outp);
}

// Round 18
// 58.229 us; speedup vs baseline: 1.0506x; 1.0506x over previous
//
#include <hip/hip_runtime.h>
#include <cmath>

typedef float  f32x4  __attribute__((ext_vector_type(4)));
typedef __bf16 bf16x8 __attribute__((ext_vector_type(8)));
typedef unsigned int u32x4 __attribute__((ext_vector_type(4)));
typedef unsigned int u32x2 __attribute__((ext_vector_type(2)));
typedef unsigned int   u32;
typedef unsigned short u16;

#define HEAD_DIM 64
#define N_HEADS  25
#define N_KV     5
#define WINDOW   1024
#define N_META   128
#define B_       2
#define T_       2048
#define QB       64
#define NTILES   (T_ / 64)
#define TILE_U32 2048               // 64 rows x 32 u32 (8 KB)
// Constant softmax bias: S*0.125*log2e <= (8*1.5)^2*0.125*1.443 ~= 26 (RMSNorm-guaranteed,
// w in [0.5,1.5]). exp2(S-20) <= 64; l <= 6.6e4; min ~= 2^-46 (normal). Scale cancels in O/l.
#define SM_BIAS  (-20.0f)

static __device__ __forceinline__ u16 bf16_bits(float f) {
  __bf16 h = (__bf16)f;
  return __builtin_bit_cast(u16, h);
}
static __device__ __forceinline__ u32 pack2(float lo, float hi) {
  return ((u32)bf16_bits(hi) << 16) | bf16_bits(lo);
}
static __device__ __forceinline__ float fexp2(float x) {
  return __builtin_amdgcn_exp2f(x);    // bare v_exp_f32; exp2(-inf)=0
}
static __device__ __forceinline__ void gload16(const u32* g, u32* l) {
  __builtin_amdgcn_global_load_lds((const __attribute__((address_space(1))) u32*)g,
                                   (__attribute__((address_space(3))) u32*)l, 16, 0, 0);
}

// ---------------- Kernel 1 (merged prep): V-tiles (blk<320) + K-rows (blk>=320) --------
// K ws: [b][kvh][tile][key(64)][seg_phys(8) x 4 u32]; seg_phys = seg_log ^ (key&7)
// V ws: [b][kvh][tile][d(64)][32 u32]; col c=16a+8b+2g+e at seg (4a+g)^(d&7), slot 2b+e
__global__ __launch_bounds__(256) void prep_kernel(
    const float* __restrict__ k_in, const float* __restrict__ k_w,
    const float* __restrict__ v_in, const int* __restrict__ pos_ids,
    u32* __restrict__ k_ws, u32* __restrict__ v_ws)
{
  const int blk = blockIdx.x;
  const int tid = threadIdx.x;

  if (blk < B_ * N_KV * NTILES) {
    // ---------------- V transpose tile ----------------
    int tile = blk & (NTILES - 1);
    int bk   = blk >> 5;
    int kvh  = bk % N_KV, b = bk / N_KV;
    int t0   = tile * 64;

    __shared__ u16 Tl[64][72];           // [d][key]

    #pragma unroll
    for (int it = 0; it < 4; ++it) {
      int idx = it * 256 + tid;
      int kl = idx >> 4, dq = idx & 15;
      const float4 f = *(const float4*)&v_in[((size_t)(b * T_ + t0 + kl)) * (N_KV * HEAD_DIM) + kvh * HEAD_DIM + dq * 4];
      Tl[dq * 4 + 0][kl] = bf16_bits(f.x);
      Tl[dq * 4 + 1][kl] = bf16_bits(f.y);
      Tl[dq * 4 + 2][kl] = bf16_bits(f.z);
      Tl[dq * 4 + 3][kl] = bf16_bits(f.w);
    }
    __syncthreads();

    u32* outb = v_ws + (size_t)blk * TILE_U32;
    #pragma unroll
    for (int it = 0; it < 8; ++it) {
      int o = it * 256 + tid;
      int d = o >> 5, c = o & 31;
      u32 w = ((u32)Tl[d][2 * c + 1] << 16) | Tl[d][2 * c];
      int a = c >> 4, bs = (c >> 3) & 1, gp = (c >> 1) & 3, e = c & 1;
      int sp = (4 * a + gp) ^ (d & 7);
      outb[d * 32 + sp * 4 + 2 * bs + e] = w;
    }
    return;
  }

  // ---------------- K RMSNorm + RoPE rows ----------------
  int gw   = (((blk - B_ * N_KV * NTILES) * 256 + tid) >> 6);
  int lane = tid & 63;
  if (gw >= B_ * T_ * N_KV) return;
  int kvh = gw % N_KV;
  int bt  = gw / N_KV;

  float x = k_in[(size_t)bt * (N_KV * HEAD_DIM) + kvh * HEAD_DIM + lane];
  float ss = x * x;
  #pragma unroll
  for (int off = 32; off; off >>= 1) ss += __shfl_xor(ss, off);
  float y = k_w[lane] * x * rsqrtf(ss * (1.f / 64.f) + 1e-6f);

  int   pos = pos_ids[bt];
  float ang = (float)pos * powf(10000.f, -(float)(lane & 31) * (1.f / 32.f));
  float c, s;
  sincosf(ang, &s, &c);              // sincosf(x, sin*, cos*)
  float part = __shfl_xor(y, 32);
  float r = (lane < 32) ? (y * c - part * s) : (y * c + part * s);

  u16 mybits = bf16_bits(r);
  u32 pb = (u32)(u16)__shfl_xor((int)mybits, 1);
  u32 w  = (pb << 16) | mybits;
  int b = bt / T_, t = bt % T_;
  if (!(lane & 1)) {
    int c32 = lane >> 1;
    int kl = t & 63, tile = t >> 6;
    int sp = (c32 >> 2) ^ (kl & 7);
    k_ws[(((size_t)(b * N_KV + kvh) * NTILES + tile)) * TILE_U32 + kl * 32 + sp * 4 + (c32 & 3)] = w;
  }
}

// ---------------- Kernel 2: fused MFMA flash attention (r16 structure, best=60.8us) ----
__global__ __launch_bounds__(256, 4) void attn_kernel(
    const float* __restrict__ q_in, const float* __restrict__ q_w,
    const int* __restrict__ pos_ids,
    const u32* __restrict__ kws, const u32* __restrict__ vws,
    float* __restrict__ out)
{
  // XCD-affinity + LPT decode (r14; FETCH 44.8->16.5MB proven).
  const int i  = blockIdx.x;
  const int x  = i & 7, k = i >> 3;
  const int gA = (5 * x) >> 2;
  const int a0 = 200 * x - 160 * gA;
  const int nB = 40 + a0;
  int grp, j_;
  if (k < nB) { grp = gA + 1; j_ = k; }
  else        { grp = gA;     j_ = a0 + (k - nB); }
  const int qt  = 31 - j_ / 5;
  const int hh  = j_ % 5;
  const int b   = grp / 5;
  const int kvh = grp % 5;
  const int h   = kvh * 5 + hh;
  const int qb  = qt * QB;
  const int tid = threadIdx.x, wid = tid >> 6, lane = tid & 63;
  const int l15 = lane & 15, g = lane >> 4;
  const int qrow0 = wid * 16;

  __shared__ u32 Ks[2 * TILE_U32];       // K tiles (buf1 doubles as Q staging pre-loop)
  __shared__ u32 Vt[2 * TILE_U32];       // V^T tiles

  const int nt    = (qt <= 18) ? (qt + 1) : 19;
  const int shift = qt - 18;

  const size_t kvbase = ((size_t)(b * N_KV + kvh)) * NTILES * TILE_U32;
  const u32* kb = kws + kvbase;
  const u32* vb = vws + kvbase;

  // ---- issue tile-0 staging first (hides under Q-staging compute) ----
  #pragma unroll
  for (int j = 0; j < 4; ++j) {
    int ci = (wid << 2) | j;
    if (ci < 8) gload16(kb + ci * 256 + lane * 4, &Ks[ci * 256]);
    else        gload16(vb + (ci - 8) * 256 + lane * 4, &Vt[(ci - 8) * 256]);
  }

  // ---- Q staging, 4-rows-parallel: lane (g,l15) does row 4*it+g, d = 4*l15..4*l15+3 ----
  {
    const int   jbase = (4 * l15) & 31;
    const float r32   = 0.74989420933f;            // 10000^(-1/32)
    float fr[4];
    fr[0] = powf(10000.f, -(float)jbase * (1.f / 32.f));
    fr[1] = fr[0] * r32; fr[2] = fr[1] * r32; fr[3] = fr[2] * r32;

    const int t0g = b * T_ + qb + qrow0;
    int pos_prev = pos_ids[t0g + g];
    float cc[4], sn[4], c4[4], s4[4];
    #pragma unroll
    for (int e = 0; e < 4; ++e) {
      sincosf((float)pos_prev * fr[e], &sn[e], &cc[e]);   // sincosf(x, sin*, cos*)
      sincosf(4.f * fr[e], &s4[e], &c4[e]);
    }
    const float4 wv = *(const float4*)&q_w[4 * l15];
    #pragma unroll
    for (int it = 0; it < 4; ++it) {
      const int row = 4 * it + g;
      if (it) {
        int pos = pos_ids[t0g + row];
        if (__all(pos == pos_prev + 4)) {
          #pragma unroll
          for (int e = 0; e < 4; ++e) {
            float c2 = cc[e] * c4[e] - sn[e] * s4[e];
            sn[e] = sn[e] * c4[e] + cc[e] * s4[e];
            cc[e] = c2;
          }
        } else {
          #pragma unroll
          for (int e = 0; e < 4; ++e) sincosf((float)pos * fr[e], &sn[e], &cc[e]);
        }
        pos_prev = pos;
      }
      const float4 xv = *(const float4*)&q_in[((size_t)(t0g + row)) * (N_HEADS * HEAD_DIM) + h * HEAD_DIM + 4 * l15];
      float ss = xv.x * xv.x + xv.y * xv.y + xv.z * xv.z + xv.w * xv.w;
      ss += __shfl_xor(ss, 1); ss += __shfl_xor(ss, 2);
      ss += __shfl_xor(ss, 4); ss += __shfl_xor(ss, 8);
      const float rn = rsqrtf(ss * (1.f / 64.f) + 1e-6f);
      float y[4] = {wv.x * xv.x * rn, wv.y * xv.y * rn, wv.z * xv.z * rn, wv.w * xv.w * rn};
      float rv[4];
      #pragma unroll
      for (int e = 0; e < 4; ++e) {
        float part = __shfl_xor(y[e], 8);
        rv[e] = ((l15 < 8) ? (y[e] * cc[e] - part * sn[e])
                           : (y[e] * cc[e] + part * sn[e])) * 0.18033688f;
      }
      u32x2 w2;
      w2.x = pack2(rv[0], rv[1]);
      w2.y = pack2(rv[2], rv[3]);
      *(u32x2*)&Ks[TILE_U32 + (qrow0 + row) * 32 + 2 * l15] = w2;
    }
  }
  __syncthreads();                       // tile0 loads drained + Q rows visible

  bf16x8 qf[2];
  #pragma unroll
  for (int ks = 0; ks < 2; ++ks)
    qf[ks] = *(const bf16x8*)&Ks[TILE_U32 + (qrow0 + l15) * 32 + 16 * ks + 4 * g];
  __syncthreads();                       // all qf reads done before buf1 is overwritten

  float l_part = 0.f;                    // per-lane partial of l (g-reduce deferred)
  f32x4 acc_o[4];
  #pragma unroll
  for (int mt = 0; mt < 4; ++mt) acc_o[mt] = (f32x4)(0.f);

  const int q_abs = qb + qrow0 + l15;

  int buf = 0;
  for (int i2 = 0; i2 < nt; ++i2) {
    // ---- prefetch next tile into buf^1 ----
    if (i2 + 1 < nt) {
      int tn = (qt <= 18 || i2 + 1 < 2) ? (i2 + 1) : (i2 + 1 + shift);
      const u32* kt = kb + (size_t)tn * TILE_U32;
      const u32* vt = vb + (size_t)tn * TILE_U32;
      u32* kd = &Ks[(buf ^ 1) * TILE_U32];
      u32* vd = &Vt[(buf ^ 1) * TILE_U32];
      #pragma unroll
      for (int j = 0; j < 4; ++j) {
        int ci = (wid << 2) | j;
        if (ci < 8) gload16(kt + ci * 256 + lane * 4, kd + ci * 256);
        else        gload16(vt + (ci - 8) * 256 + lane * 4, vd + (ci - 8) * 256);
      }
    }
    const int k0 = ((qt <= 18 || i2 < 2) ? i2 : i2 + shift) << 6;

    // ---- S^T - 20 = K·Q^T + C(-20)  (bias folded into MFMA C-init) ----
    f32x4 accs[4];
    #pragma unroll
    for (int mt = 0; mt < 4; ++mt) accs[mt] = (f32x4)(SM_BIAS);
    #pragma unroll
    for (int ks = 0; ks < 2; ++ks) {
      #pragma unroll
      for (int mt = 0; mt < 4; ++mt) {
        bf16x8 kf = *(const bf16x8*)&Ks[buf * TILE_U32 + (16 * mt + l15) * 32 + (((4 * ks + g) ^ (l15 & 7)) << 2)];
        accs[mt] = __builtin_amdgcn_mfma_f32_16x16x32_bf16(kf, qf[ks], accs[mt], 0, 0, 0);
      }
    }

    // ---- mask boundary tiles, then P = exp2(S - 20) directly (no max tracking) ----
    const bool do_mask = (i2 == nt - 1) || (qt >= 18 && i2 == 2);
    if (do_mask) {
      #pragma unroll
      for (int mt = 0; mt < 4; ++mt)
        #pragma unroll
        for (int rg = 0; rg < 4; ++rg) {
          int key = k0 + 16 * mt + 4 * g + rg;
          bool ok = (key <= q_abs) && ((key >= q_abs - (WINDOW - 1)) || (key < N_META));
          accs[mt][rg] = ok ? accs[mt][rg] : -INFINITY;
        }
    }
    float rsum = 0.f;
    #pragma unroll
    for (int mt = 0; mt < 4; ++mt)
      #pragma unroll
      for (int rg = 0; rg < 4; ++rg) {
        float pi = fexp2(accs[mt][rg]);          // exp2(-inf) = 0 for masked
        accs[mt][rg] = pi;
        rsum += pi;
      }
    l_part += rsum;                      // per-lane partial; reduce in epilogue

    // ---- O += P·V, P in-register (permuted-K mfma; V b128 in matching order) ----
    #pragma unroll
    for (int ks2 = 0; ks2 < 2; ++ks2) {
      const int m0 = 2 * ks2, m1 = 2 * ks2 + 1;
      u32x4 aw;
      aw.x = pack2(accs[m0][0], accs[m0][1]);
      aw.y = pack2(accs[m0][2], accs[m0][3]);
      aw.z = pack2(accs[m1][0], accs[m1][1]);
      aw.w = pack2(accs[m1][2], accs[m1][3]);
      bf16x8 af = __builtin_bit_cast(bf16x8, aw);
      #pragma unroll
      for (int mt2 = 0; mt2 < 4; ++mt2) {
        bf16x8 vf = *(const bf16x8*)&Vt[buf * TILE_U32 + (16 * mt2 + l15) * 32 + (((4 * ks2 + g) ^ (l15 & 7)) << 2)];
        acc_o[mt2] = __builtin_amdgcn_mfma_f32_16x16x32_bf16(af, vf, acc_o[mt2], 0, 0, 0);
      }
    }

    __syncthreads();     // drains vmcnt (next tile landed) + all waves done with buf
    buf ^= 1;
  }

  // ---- epilogue: reduce l across g-groups once, divide, store ----
  float lsum = l_part;
  lsum += __shfl_xor(lsum, 16);
  lsum += __shfl_xor(lsum, 32);
  float l4[4];
  #pragma unroll
  for (int rg = 0; rg < 4; ++rg) l4[rg] = __shfl(lsum, 4 * g + rg);
  #pragma unroll
  for (int mt2 = 0; mt2 < 4; ++mt2)
    #pragma unroll
    for (int rg = 0; rg < 4; ++rg) {
      int t = qb + qrow0 + 4 * g + rg;
      out[((size_t)(b * T_ + t)) * (N_HEADS * HEAD_DIM) + h * HEAD_DIM + 16 * mt2 + l15] =
          acc_o[mt2][rg] / l4[rg];
    }
}

extern "C" void kernel_launch(void* const* d_in, const int* in_sizes, int n_in,
                              void* d_out, int out_size, void* d_ws, size_t ws_size,
                              hipStream_t stream) {
  const float* q   = (const float*)d_in[0];
  const float* k   = (const float*)d_in[1];
  const float* v   = (const float*)d_in[2];
  const float* qw  = (const float*)d_in[3];
  const float* kw  = (const float*)d_in[4];
  const int*   pos = (const int*)d_in[5];

  u32* kp = (u32*)d_ws;                                    // 2.62 MB
  u32* vp = kp + (size_t)B_ * N_KV * NTILES * TILE_U32;    // 2.62 MB
  float* outp = (float*)d_out;

  // merged prep: 320 V-tile blocks + 5120 K-row blocks in one launch
  prep_kernel<<<B_ * N_KV * NTILES + 5120, 256, 0, stream>>>(k, kw, v, pos, kp, vp);
  attn_kernel<<<1600, 256, 0, stream>>>(q, qw, pos, kp, vp, outp);
}